// Round 4
// baseline (421.942 us; speedup 1.0000x reference)
//
#include <hip/hip_runtime.h>
#include <hip/hip_bf16.h>

#define O_N 128
#define D_N 128
#define F_LS 64
#define T_MAX 128
#define FE_N 16
#define H_GRU 64
#define NH 128
#define NO 64
#define PH 128

typedef _Float16 f16;
typedef f16 f16x8 __attribute__((ext_vector_type(8)));
typedef float f32x4 __attribute__((ext_vector_type(4)));

__device__ __forceinline__ float fast_sigmoid(float x) {
    return __builtin_amdgcn_rcpf(1.f + __expf(-x));
}

// ---------------- encoders + PA/PB precompute (also zeroes d_out) ----------
__global__ __launch_bounds__(128) void k_enc(
    const float* __restrict__ O_feats, const float* __restrict__ D_feats,
    const float* __restrict__ WO1, const float* __restrict__ bO1,
    const float* __restrict__ WO2, const float* __restrict__ bO2,
    const float* __restrict__ WO3, const float* __restrict__ bO3,
    const float* __restrict__ WD1, const float* __restrict__ bD1,
    const float* __restrict__ WD2, const float* __restrict__ bD2,
    const float* __restrict__ WD3, const float* __restrict__ bD3,
    const float* __restrict__ Wp1,
    float* __restrict__ PA, float* __restrict__ PB, float* __restrict__ d_out)
{
    __shared__ float h1[NH];
    __shared__ float h2[NH];
    __shared__ float ev[NO];
    const int b = blockIdx.x;
    const int enc = b >> 7;
    const int row = b & 127;
    const int t = threadIdx.x;
    if (b == 0 && t == 0) d_out[0] = 0.f;

    const float* x  = (enc ? D_feats : O_feats) + row * F_LS;
    const float* W1 = enc ? WD1 : WO1;  const float* b1 = enc ? bD1 : bO1;
    const float* W2 = enc ? WD2 : WO2;  const float* b2 = enc ? bD2 : bO2;
    const float* W3 = enc ? WD3 : WO3;  const float* b3 = enc ? bD3 : bO3;

    float a = b1[t];
    #pragma unroll 8
    for (int k = 0; k < F_LS; ++k) a += x[k] * W1[k * NH + t];
    h1[t] = fmaxf(a, 0.f);
    __syncthreads();

    a = b2[t];
    #pragma unroll 8
    for (int k = 0; k < NH; ++k) a += h1[k] * W2[k * NH + t];
    h2[t] = fmaxf(a, 0.f);
    __syncthreads();

    if (t < NO) {
        a = b3[t];
        #pragma unroll 8
        for (int k = 0; k < NH; ++k) a += h2[k] * W3[k * NO + t];
        ev[t] = a;
    }
    __syncthreads();

    const float* Wp = Wp1 + (enc ? NO * PH : 0);
    a = 0.f;
    #pragma unroll 8
    for (int k = 0; k < NO; ++k) a += ev[k] * Wp[k * PH + t];
    (enc ? PB : PA)[row * PH + t] = a;
}

// ---------------- pair scores ----------------
__global__ __launch_bounds__(128) void k_pair(
    const float* __restrict__ PA, const float* __restrict__ PB,
    const float* __restrict__ bp1, const float* __restrict__ Wp2,
    const float* __restrict__ bp2, float* __restrict__ s_pair)
{
    const int i = blockIdx.x;
    const int j = threadIdx.x;
    __shared__ float pa[PH];
    __shared__ float b1s[PH];
    __shared__ float w2s[PH];
    pa[j]  = PA[i * PH + j];
    b1s[j] = bp1[j];
    w2s[j] = Wp2[j];
    __syncthreads();
    const float* pb = PB + j * PH;
    float acc = 0.f;
    #pragma unroll 8
    for (int c = 0; c < PH; ++c)
        acc += w2s[c] * fmaxf(pa[c] + pb[c] + b1s[c], 0.f);
    float z = acc + bp2[0];
    float sp = fmaxf(z, 0.f) + log1pf(__expf(-fabsf(z)));
    s_pair[i * 128 + j] = sp;
}

// ------- GRU: ONE wave per 16 pairs, no barriers, exp2-folded gates -------
// grid 1024 x 64 threads (1 wave/SIMD). LDS h round-trip is wave-internal
// (in-order DS pipe -> lgkmcnt only, NO s_barrier, NO vmcnt drain).
__global__ __launch_bounds__(64) void k_gru(
    const float* __restrict__ seqs, const int* __restrict__ lengths,
    const float* __restrict__ W_ih, const float* __restrict__ b_ih,
    const float* __restrict__ W_hh, const float* __restrict__ b_hh,
    const float* __restrict__ Ws, const float* __restrict__ bs,
    const float* __restrict__ s_pair, float* __restrict__ d_out)
{
    __shared__ __align__(16) f16 hbuf[16 * 72];   // [pair][64 + 8 pad]
    const int l = threadIdx.x;
    const int q = l >> 4, n = l & 15;
    const int pb = blockIdx.x * 16;
    // gate pre-scales: sigmoid(a)=rcp(1+exp2(-a*log2e)); tanh(u)=1-2*rcp(1+exp2(2u*log2e))
    const float S_RZ = -1.4426950408889634f;   // -log2(e)
    const float S_N  =  2.8853900817779268f;   // 2*log2(e)

    // B-fragments, scales folded: lane holds W[k = ks*32 + q*8 + j][16*nt + n]
    f16x8 whh[12][2], wih[12];
    #pragma unroll
    for (int nt = 0; nt < 12; ++nt) {
        const float s = (nt < 8) ? S_RZ : S_N;
        #pragma unroll
        for (int ks = 0; ks < 2; ++ks)
            #pragma unroll
            for (int j = 0; j < 8; ++j)
                whh[nt][ks][j] = (f16)(W_hh[(ks * 32 + q * 8 + j) * 192 + nt * 16 + n] * s);
        #pragma unroll
        for (int j = 0; j < 8; ++j) {
            int k = q * 8 + j;
            wih[nt][j] = (k < FE_N) ? (f16)(W_ih[k * 192 + nt * 16 + n] * s) : (f16)0.f;
        }
    }
    // biases folded into accumulator init (scaled), per col c = 16ct + n
    float brz[8], bhn[4], bxn[4], wsc[4];
    #pragma unroll
    for (int ct = 0; ct < 4; ++ct) {
        int c = ct * 16 + n;
        brz[ct]     = S_RZ * (b_ih[c] + b_hh[c]);
        brz[4 + ct] = S_RZ * (b_ih[64 + c] + b_hh[64 + c]);
        bhn[ct]     = S_N * b_hh[128 + c];
        bxn[ct]     = S_N * b_ih[128 + c];
        wsc[ct]     = Ws[c];
    }
    int len[4];
    #pragma unroll
    for (int r = 0; r < 4; ++r) len[r] = lengths[pb + q * 4 + r];
    int ml = max(max(len[0], len[1]), max(len[2], len[3]));
    ml = max(ml, __shfl_xor(ml, 16));
    ml = max(ml, __shfl_xor(ml, 32));
    const int maxlen = __builtin_amdgcn_readfirstlane(ml);

    // zero h (144 f16x8 chunks)
    {
        f16x8 z8 = {(f16)0, (f16)0, (f16)0, (f16)0, (f16)0, (f16)0, (f16)0, (f16)0};
        *(f16x8*)&hbuf[l * 8] = z8;
        *(f16x8*)&hbuf[(l + 64) * 8] = z8;
        if (l < 16) *(f16x8*)&hbuf[(l + 128) * 8] = z8;
    }

    // x: lanes q<2 stream pair n's row from global, 1-step prefetch
    const float4* xp = (const float4*)(seqs + (size_t)(pb + n) * (T_MAX * FE_N)) + q * 2;
    float4 xa = {0.f, 0.f, 0.f, 0.f}, xb = xa;
    if (q < 2) { xa = xp[0]; xb = xp[1]; }

    f32x4 hold[4];
    #pragma unroll
    for (int ct = 0; ct < 4; ++ct) hold[ct] = (f32x4){0.f, 0.f, 0.f, 0.f};
    const f16x8 zero8 = {(f16)0, (f16)0, (f16)0, (f16)0, (f16)0, (f16)0, (f16)0, (f16)0};

    for (int t = 0; t < maxlen; ++t) {
        f16x8 ax = zero8;
        if (q < 2) {
            ax[0] = (f16)xa.x; ax[1] = (f16)xa.y; ax[2] = (f16)xa.z; ax[3] = (f16)xa.w;
            ax[4] = (f16)xb.x; ax[5] = (f16)xb.y; ax[6] = (f16)xb.z; ax[7] = (f16)xb.w;
            int tn = (t + 1 < maxlen) ? (t + 1) : t;
            xa = xp[tn * 4];
            xb = xp[tn * 4 + 1];
        }
        // A-fragments of h (wave-internal LDS, in-order after last step's writes)
        f16x8 ah0 = *(const f16x8*)&hbuf[n * 72 + q * 8];
        f16x8 ah1 = *(const f16x8*)&hbuf[n * 72 + 32 + q * 8];

        #pragma unroll
        for (int ct = 0; ct < 4; ++ct) {
            f32x4 ar = {brz[ct], brz[ct], brz[ct], brz[ct]};
            ar = __builtin_amdgcn_mfma_f32_16x16x32_f16(ax,  wih[ct],    ar, 0, 0, 0);
            ar = __builtin_amdgcn_mfma_f32_16x16x32_f16(ah0, whh[ct][0], ar, 0, 0, 0);
            ar = __builtin_amdgcn_mfma_f32_16x16x32_f16(ah1, whh[ct][1], ar, 0, 0, 0);
            f32x4 az = {brz[4+ct], brz[4+ct], brz[4+ct], brz[4+ct]};
            az = __builtin_amdgcn_mfma_f32_16x16x32_f16(ax,  wih[4+ct],    az, 0, 0, 0);
            az = __builtin_amdgcn_mfma_f32_16x16x32_f16(ah0, whh[4+ct][0], az, 0, 0, 0);
            az = __builtin_amdgcn_mfma_f32_16x16x32_f16(ah1, whh[4+ct][1], az, 0, 0, 0);
            f32x4 hn = {bhn[ct], bhn[ct], bhn[ct], bhn[ct]};
            hn = __builtin_amdgcn_mfma_f32_16x16x32_f16(ah0, whh[8+ct][0], hn, 0, 0, 0);
            hn = __builtin_amdgcn_mfma_f32_16x16x32_f16(ah1, whh[8+ct][1], hn, 0, 0, 0);
            f32x4 xn = {bxn[ct], bxn[ct], bxn[ct], bxn[ct]};
            xn = __builtin_amdgcn_mfma_f32_16x16x32_f16(ax, wih[8+ct], xn, 0, 0, 0);

            // C/D: row(pair) = 4q + r, col = 16ct + n
            #pragma unroll
            for (int r = 0; r < 4; ++r) {
                float rg    = __builtin_amdgcn_rcpf(1.f + __builtin_amdgcn_exp2f(ar[r]));
                float zg    = __builtin_amdgcn_rcpf(1.f + __builtin_amdgcn_exp2f(az[r]));
                float inner = fmaf(rg, hn[r], xn[r]);
                float nn    = fmaf(-2.f, __builtin_amdgcn_rcpf(1.f + __builtin_amdgcn_exp2f(inner)), 1.f);
                float hv    = hold[ct][r];
                float hnew  = fmaf(zg, hv - nn, nn);
                hnew = (t < len[r]) ? hnew : hv;
                hold[ct][r] = hnew;
                hbuf[(q * 4 + r) * 72 + ct * 16 + n] = (f16)hnew;
            }
        }
    }

    // epilogue: p_seq = sigmoid(h @ Ws + bs); contrib = s_pair * p_seq
    float part[4];
    #pragma unroll
    for (int r = 0; r < 4; ++r)
        part[r] = hold[0][r] * wsc[0] + hold[1][r] * wsc[1] +
                  hold[2][r] * wsc[2] + hold[3][r] * wsc[3];
    #pragma unroll
    for (int off = 1; off < 16; off <<= 1)
        #pragma unroll
        for (int r = 0; r < 4; ++r)
            part[r] += __shfl_xor(part[r], off);

    float contrib = 0.f;
    if (n == 0) {
        float bsv = bs[0];
        #pragma unroll
        for (int r = 0; r < 4; ++r) {
            float pv = fast_sigmoid(part[r] + bsv);
            contrib += s_pair[pb + q * 4 + r] * pv;
        }
    }
    contrib += __shfl_xor(contrib, 16);
    contrib += __shfl_xor(contrib, 32);
    if (l == 0) atomicAdd(d_out, contrib);
}

extern "C" void kernel_launch(void* const* d_in, const int* in_sizes, int n_in,
                              void* d_out, int out_size, void* d_ws, size_t ws_size,
                              hipStream_t stream)
{
    const float* O_feats = (const float*)d_in[0];
    const float* D_feats = (const float*)d_in[1];
    const float* seqs    = (const float*)d_in[2];
    const int*   lengths = (const int*)d_in[3];
    const float* WO1 = (const float*)d_in[4];  const float* bO1 = (const float*)d_in[5];
    const float* WO2 = (const float*)d_in[6];  const float* bO2 = (const float*)d_in[7];
    const float* WO3 = (const float*)d_in[8];  const float* bO3 = (const float*)d_in[9];
    const float* WD1 = (const float*)d_in[10]; const float* bD1 = (const float*)d_in[11];
    const float* WD2 = (const float*)d_in[12]; const float* bD2 = (const float*)d_in[13];
    const float* WD3 = (const float*)d_in[14]; const float* bD3 = (const float*)d_in[15];
    const float* Wp1 = (const float*)d_in[16]; const float* bp1 = (const float*)d_in[17];
    const float* Wp2 = (const float*)d_in[18]; const float* bp2 = (const float*)d_in[19];
    const float* W_ih = (const float*)d_in[20]; const float* b_ih = (const float*)d_in[21];
    const float* W_hh = (const float*)d_in[22]; const float* b_hh = (const float*)d_in[23];
    const float* Ws   = (const float*)d_in[24]; const float* bs   = (const float*)d_in[25];

    float* out    = (float*)d_out;
    float* PA     = (float*)d_ws;              // 16384 f
    float* PB     = PA + 128 * 128;            // 16384 f
    float* s_pair = PB + 128 * 128;            // 16384 f

    k_enc<<<256, 128, 0, stream>>>(O_feats, D_feats,
                                   WO1, bO1, WO2, bO2, WO3, bO3,
                                   WD1, bD1, WD2, bD2, WD3, bD3,
                                   Wp1, PA, PB, out);
    k_pair<<<128, 128, 0, stream>>>(PA, PB, bp1, Wp2, bp2, s_pair);
    k_gru<<<1024, 64, 0, stream>>>(seqs, lengths, W_ih, b_ih, W_hh, b_hh,
                                   Ws, bs, s_pair, out);
}

// Round 5
// 371.961 us; speedup vs baseline: 1.1344x; 1.1344x over previous
//
#include <hip/hip_runtime.h>
#include <hip/hip_bf16.h>

#define O_N 128
#define D_N 128
#define F_LS 64
#define T_MAX 128
#define FE_N 16
#define H_GRU 64
#define NH 128
#define NO 64
#define PH 128
#define NG 1024

typedef _Float16 f16;
typedef f16 f16x8 __attribute__((ext_vector_type(8)));
typedef float f32x4 __attribute__((ext_vector_type(4)));

__device__ __forceinline__ float fast_sigmoid(float x) {
    return __builtin_amdgcn_rcpf(1.f + __expf(-x));
}

// ---------------- encoders + PA/PB precompute (also zeroes d_out) ----------
__global__ __launch_bounds__(128) void k_enc(
    const float* __restrict__ O_feats, const float* __restrict__ D_feats,
    const float* __restrict__ WO1, const float* __restrict__ bO1,
    const float* __restrict__ WO2, const float* __restrict__ bO2,
    const float* __restrict__ WO3, const float* __restrict__ bO3,
    const float* __restrict__ WD1, const float* __restrict__ bD1,
    const float* __restrict__ WD2, const float* __restrict__ bD2,
    const float* __restrict__ WD3, const float* __restrict__ bD3,
    const float* __restrict__ Wp1,
    float* __restrict__ PA, float* __restrict__ PB, float* __restrict__ d_out)
{
    __shared__ float h1[NH];
    __shared__ float h2[NH];
    __shared__ float ev[NO];
    const int b = blockIdx.x;
    const int enc = b >> 7;
    const int row = b & 127;
    const int t = threadIdx.x;
    if (b == 0 && t == 0) d_out[0] = 0.f;

    const float* x  = (enc ? D_feats : O_feats) + row * F_LS;
    const float* W1 = enc ? WD1 : WO1;  const float* b1 = enc ? bD1 : bO1;
    const float* W2 = enc ? WD2 : WO2;  const float* b2 = enc ? bD2 : bO2;
    const float* W3 = enc ? WD3 : WO3;  const float* b3 = enc ? bD3 : bO3;

    float a = b1[t];
    #pragma unroll 8
    for (int k = 0; k < F_LS; ++k) a += x[k] * W1[k * NH + t];
    h1[t] = fmaxf(a, 0.f);
    __syncthreads();

    a = b2[t];
    #pragma unroll 8
    for (int k = 0; k < NH; ++k) a += h1[k] * W2[k * NH + t];
    h2[t] = fmaxf(a, 0.f);
    __syncthreads();

    if (t < NO) {
        a = b3[t];
        #pragma unroll 8
        for (int k = 0; k < NH; ++k) a += h2[k] * W3[k * NO + t];
        ev[t] = a;
    }
    __syncthreads();

    const float* Wp = Wp1 + (enc ? NO * PH : 0);
    a = 0.f;
    #pragma unroll 8
    for (int k = 0; k < NO; ++k) a += ev[k] * Wp[k * PH + t];
    (enc ? PB : PA)[row * PH + t] = a;
}

// ---------------- pair scores ----------------
__global__ __launch_bounds__(128) void k_pair(
    const float* __restrict__ PA, const float* __restrict__ PB,
    const float* __restrict__ bp1, const float* __restrict__ Wp2,
    const float* __restrict__ bp2, float* __restrict__ s_pair)
{
    const int i = blockIdx.x;
    const int j = threadIdx.x;
    __shared__ float pa[PH];
    __shared__ float b1s[PH];
    __shared__ float w2s[PH];
    pa[j]  = PA[i * PH + j];
    b1s[j] = bp1[j];
    w2s[j] = Wp2[j];
    __syncthreads();
    const float* pb = PB + j * PH;
    float acc = 0.f;
    #pragma unroll 8
    for (int c = 0; c < PH; ++c)
        acc += w2s[c] * fmaxf(pa[c] + pb[c] + b1s[c], 0.f);
    float z = acc + bp2[0];
    float sp = fmaxf(z, 0.f) + log1pf(__expf(-fabsf(z)));
    s_pair[i * 128 + j] = sp;
}

// ------- counting sort by length, DESCENDING, one block, LDS atomics -------
__global__ __launch_bounds__(1024) void k_sort(
    const int* __restrict__ lengths, int* __restrict__ perm)
{
    __shared__ int cnt[130];
    __shared__ int suf[130];
    const int t = threadIdx.x;
    if (t < 130) cnt[t] = 0;
    __syncthreads();
    for (int i = t; i < 16384; i += 1024) atomicAdd(&cnt[lengths[i]], 1);
    __syncthreads();
    if (t < 130) suf[t] = cnt[t];
    __syncthreads();
    for (int d = 1; d < 130; d <<= 1) {
        int v = 0;
        if (t < 130) { v = suf[t]; if (t + d < 130) v += suf[t + d]; }
        __syncthreads();
        if (t < 130) suf[t] = v;
        __syncthreads();
    }
    if (t < 129) cnt[t] = (t + 1 < 130) ? suf[t + 1] : 0;
    __syncthreads();
    for (int i = t; i < 16384; i += 1024) {
        int pos = atomicAdd(&cnt[lengths[i]], 1);
        perm[pos] = i;
    }
}

// ---- GRU: 4 waves per 16-pair group (16 cols each), exp2-folded gates ----
// grid 1024 x 256 (4 blocks/CU); wave w owns cols [16w,16w+16)
__global__ __launch_bounds__(256, 4) void k_gru(
    const float* __restrict__ seqs, const int* __restrict__ lengths,
    const int* __restrict__ perm,
    const float* __restrict__ W_ih, const float* __restrict__ b_ih,
    const float* __restrict__ W_hh, const float* __restrict__ b_hh,
    const float* __restrict__ Ws, const float* __restrict__ bs,
    const float* __restrict__ s_pair, float* __restrict__ d_out)
{
    __shared__ __align__(16) f16 hbuf[2 * 1152];   // [buf][pair][64 + 8 pad]
    __shared__ float red[64];
    const int tid = threadIdx.x;
    const int w  = tid >> 6;
    const int l  = tid & 63;
    const int q  = l >> 4;
    const int n  = l & 15;
    const int c  = w * 16 + n;
    const int pb = blockIdx.x * 16;
    const float S_RZ = -1.4426950408889634f;   // -log2(e)
    const float S_N  =  2.8853900817779268f;   // 2*log2(e)

    // B-fragments (pre-scaled): lane holds W[k = ks*32 + q*8 + j][gate*64 + c]
    f16x8 wh[3][2], wi[3];
    #pragma unroll
    for (int g = 0; g < 3; ++g) {
        const int gb = g * 64;
        const float s = (g < 2) ? S_RZ : S_N;
        #pragma unroll
        for (int ks = 0; ks < 2; ++ks)
            #pragma unroll
            for (int j = 0; j < 8; ++j)
                wh[g][ks][j] = (f16)(W_hh[(ks * 32 + q * 8 + j) * 192 + gb + c] * s);
        #pragma unroll
        for (int j = 0; j < 8; ++j) {
            int k = q * 8 + j;
            wi[g][j] = (k < FE_N) ? (f16)(W_ih[k * 192 + gb + c] * s) : (f16)0.f;
        }
    }
    // persistent bias C-vectors (live across loop; MFMA reads them as C)
    const float brz_r = S_RZ * (b_ih[c] + b_hh[c]);
    const float brz_z = S_RZ * (b_ih[64 + c] + b_hh[64 + c]);
    const float bhn_s = S_N * b_hh[128 + c];
    const float bxn_s = S_N * b_ih[128 + c];
    const f32x4 c_r  = {brz_r, brz_r, brz_r, brz_r};
    const f32x4 c_z  = {brz_z, brz_z, brz_z, brz_z};
    const f32x4 c_hn = {bhn_s, bhn_s, bhn_s, bhn_s};
    const f32x4 c_xn = {bxn_s, bxn_s, bxn_s, bxn_s};
    const float wsc  = Ws[c];
    const float bsv  = bs[0];

    int len[4];
    #pragma unroll
    for (int r = 0; r < 4; ++r) len[r] = lengths[perm[pb + q * 4 + r]];
    int ml = max(max(len[0], len[1]), max(len[2], len[3]));
    ml = max(ml, __shfl_xor(ml, 16));
    ml = max(ml, __shfl_xor(ml, 32));
    const int maxlen = __builtin_amdgcn_readfirstlane(ml);

    // zero h buffer 0
    {
        f16x8 z8 = {(f16)0, (f16)0, (f16)0, (f16)0, (f16)0, (f16)0, (f16)0, (f16)0};
        if (tid < 144) *(f16x8*)&hbuf[tid * 8] = z8;
    }

    // x: lanes q<2 stream pair n's feats [8q,8q+8) from global, 1-step prefetch
    const int pp = perm[pb + n];
    const float4* xp = (const float4*)(seqs + (size_t)pp * (T_MAX * FE_N)) + q * 2;
    float4 xa = {0.f, 0.f, 0.f, 0.f}, xb = xa;
    if (q < 2) { xa = xp[0]; xb = xp[1]; }

    float hold[4] = {0.f, 0.f, 0.f, 0.f};
    const f16x8 zero8 = {(f16)0, (f16)0, (f16)0, (f16)0, (f16)0, (f16)0, (f16)0, (f16)0};
    __syncthreads();

    for (int t = 0; t < maxlen; ++t) {
        f16x8 ax = zero8;
        if (q < 2) {
            ax[0] = (f16)xa.x; ax[1] = (f16)xa.y; ax[2] = (f16)xa.z; ax[3] = (f16)xa.w;
            ax[4] = (f16)xb.x; ax[5] = (f16)xb.y; ax[6] = (f16)xb.z; ax[7] = (f16)xb.w;
            int tn = (t + 1 < maxlen) ? (t + 1) : t;
            xa = xp[tn * 4];
            xb = xp[tn * 4 + 1];
        }
        const f16* hb  = hbuf + (t & 1) * 1152;
        f16*       hbn = hbuf + ((t + 1) & 1) * 1152;

        f16x8 ah0 = *(const f16x8*)&hb[n * 72 + q * 8];
        f16x8 ah1 = *(const f16x8*)&hb[n * 72 + 32 + q * 8];

        f32x4 ar = __builtin_amdgcn_mfma_f32_16x16x32_f16(ah0, wh[0][0], c_r, 0, 0, 0);
        ar = __builtin_amdgcn_mfma_f32_16x16x32_f16(ah1, wh[0][1], ar, 0, 0, 0);
        ar = __builtin_amdgcn_mfma_f32_16x16x32_f16(ax,  wi[0],    ar, 0, 0, 0);
        f32x4 az = __builtin_amdgcn_mfma_f32_16x16x32_f16(ah0, wh[1][0], c_z, 0, 0, 0);
        az = __builtin_amdgcn_mfma_f32_16x16x32_f16(ah1, wh[1][1], az, 0, 0, 0);
        az = __builtin_amdgcn_mfma_f32_16x16x32_f16(ax,  wi[1],    az, 0, 0, 0);
        f32x4 hn = __builtin_amdgcn_mfma_f32_16x16x32_f16(ah0, wh[2][0], c_hn, 0, 0, 0);
        hn = __builtin_amdgcn_mfma_f32_16x16x32_f16(ah1, wh[2][1], hn, 0, 0, 0);
        f32x4 xn = __builtin_amdgcn_mfma_f32_16x16x32_f16(ax, wi[2], c_xn, 0, 0, 0);

        // C/D: row(pair) = 4q + r, col = c
        #pragma unroll
        for (int r = 0; r < 4; ++r) {
            float rg    = __builtin_amdgcn_rcpf(1.f + __builtin_amdgcn_exp2f(ar[r]));
            float zg    = __builtin_amdgcn_rcpf(1.f + __builtin_amdgcn_exp2f(az[r]));
            float inner = fmaf(rg, hn[r], xn[r]);
            float nn    = fmaf(-2.f, __builtin_amdgcn_rcpf(1.f + __builtin_amdgcn_exp2f(inner)), 1.f);
            float hv    = hold[r];
            float hnew  = fmaf(zg, hv - nn, nn);
            hnew = (t < len[r]) ? hnew : hv;
            hold[r] = hnew;
            hbn[(q * 4 + r) * 72 + c] = (f16)hnew;
        }
        __syncthreads();
    }

    // epilogue: p_seq = sigmoid(h @ Ws + bs); contrib = s_pair * p_seq
    float part[4];
    #pragma unroll
    for (int r = 0; r < 4; ++r) part[r] = hold[r] * wsc;
    #pragma unroll
    for (int off = 1; off < 16; off <<= 1)
        #pragma unroll
        for (int r = 0; r < 4; ++r)
            part[r] += __shfl_xor(part[r], off);
    if (n == 0) {
        #pragma unroll
        for (int r = 0; r < 4; ++r) red[w * 16 + q * 4 + r] = part[r];
    }
    __syncthreads();
    if (tid < 16) {
        float s = red[tid] + red[16 + tid] + red[32 + tid] + red[48 + tid];
        float pv = fast_sigmoid(s + bsv);
        float contrib = s_pair[perm[pb + tid]] * pv;
        #pragma unroll
        for (int off = 1; off < 16; off <<= 1)
            contrib += __shfl_xor(contrib, off);
        if (tid == 0) atomicAdd(d_out, contrib);
    }
}

extern "C" void kernel_launch(void* const* d_in, const int* in_sizes, int n_in,
                              void* d_out, int out_size, void* d_ws, size_t ws_size,
                              hipStream_t stream)
{
    const float* O_feats = (const float*)d_in[0];
    const float* D_feats = (const float*)d_in[1];
    const float* seqs    = (const float*)d_in[2];
    const int*   lengths = (const int*)d_in[3];
    const float* WO1 = (const float*)d_in[4];  const float* bO1 = (const float*)d_in[5];
    const float* WO2 = (const float*)d_in[6];  const float* bO2 = (const float*)d_in[7];
    const float* WO3 = (const float*)d_in[8];  const float* bO3 = (const float*)d_in[9];
    const float* WD1 = (const float*)d_in[10]; const float* bD1 = (const float*)d_in[11];
    const float* WD2 = (const float*)d_in[12]; const float* bD2 = (const float*)d_in[13];
    const float* WD3 = (const float*)d_in[14]; const float* bD3 = (const float*)d_in[15];
    const float* Wp1 = (const float*)d_in[16]; const float* bp1 = (const float*)d_in[17];
    const float* Wp2 = (const float*)d_in[18]; const float* bp2 = (const float*)d_in[19];
    const float* W_ih = (const float*)d_in[20]; const float* b_ih = (const float*)d_in[21];
    const float* W_hh = (const float*)d_in[22]; const float* b_hh = (const float*)d_in[23];
    const float* Ws   = (const float*)d_in[24]; const float* bs   = (const float*)d_in[25];

    float* out    = (float*)d_out;
    float* PA     = (float*)d_ws;              // 16384 f
    float* PB     = PA + 128 * 128;            // 16384 f
    float* s_pair = PB + 128 * 128;            // 16384 f
    int*   perm   = (int*)(s_pair + 16384);    // 16384 i

    k_enc<<<256, 128, 0, stream>>>(O_feats, D_feats,
                                   WO1, bO1, WO2, bO2, WO3, bO3,
                                   WD1, bD1, WD2, bD2, WD3, bD3,
                                   Wp1, PA, PB, out);
    k_pair<<<128, 128, 0, stream>>>(PA, PB, bp1, Wp2, bp2, s_pair);
    k_sort<<<1, 1024, 0, stream>>>(lengths, perm);
    k_gru<<<1024, 256, 0, stream>>>(seqs, lengths, perm, W_ih, b_ih, W_hh, b_hh,
                                    Ws, bs, s_pair, out);
}

// Round 7
// 365.644 us; speedup vs baseline: 1.1540x; 1.0173x over previous
//
#include <hip/hip_runtime.h>
#include <hip/hip_bf16.h>

#define O_N 128
#define D_N 128
#define F_LS 64
#define T_MAX 128
#define FE_N 16
#define H_GRU 64
#define NH 128
#define NO 64
#define PH 128
#define NG 1024

typedef _Float16 f16;
typedef f16 f16x4 __attribute__((ext_vector_type(4)));
typedef f16 f16x8 __attribute__((ext_vector_type(8)));
typedef float f32x4 __attribute__((ext_vector_type(4)));

__device__ __forceinline__ float fast_sigmoid(float x) {
    return __builtin_amdgcn_rcpf(1.f + __expf(-x));
}

// ---------------- encoders + PA/PB precompute (also zeroes d_out) ----------
__global__ __launch_bounds__(128) void k_enc(
    const float* __restrict__ O_feats, const float* __restrict__ D_feats,
    const float* __restrict__ WO1, const float* __restrict__ bO1,
    const float* __restrict__ WO2, const float* __restrict__ bO2,
    const float* __restrict__ WO3, const float* __restrict__ bO3,
    const float* __restrict__ WD1, const float* __restrict__ bD1,
    const float* __restrict__ WD2, const float* __restrict__ bD2,
    const float* __restrict__ WD3, const float* __restrict__ bD3,
    const float* __restrict__ Wp1,
    float* __restrict__ PA, float* __restrict__ PB, float* __restrict__ d_out)
{
    __shared__ float h1[NH];
    __shared__ float h2[NH];
    __shared__ float ev[NO];
    const int b = blockIdx.x;
    const int enc = b >> 7;
    const int row = b & 127;
    const int t = threadIdx.x;
    if (b == 0 && t == 0) d_out[0] = 0.f;

    const float* x  = (enc ? D_feats : O_feats) + row * F_LS;
    const float* W1 = enc ? WD1 : WO1;  const float* b1 = enc ? bD1 : bO1;
    const float* W2 = enc ? WD2 : WO2;  const float* b2 = enc ? bD2 : bO2;
    const float* W3 = enc ? WD3 : WO3;  const float* b3 = enc ? bD3 : bO3;

    float a = b1[t];
    #pragma unroll 8
    for (int k = 0; k < F_LS; ++k) a += x[k] * W1[k * NH + t];
    h1[t] = fmaxf(a, 0.f);
    __syncthreads();

    a = b2[t];
    #pragma unroll 8
    for (int k = 0; k < NH; ++k) a += h1[k] * W2[k * NH + t];
    h2[t] = fmaxf(a, 0.f);
    __syncthreads();

    if (t < NO) {
        a = b3[t];
        #pragma unroll 8
        for (int k = 0; k < NH; ++k) a += h2[k] * W3[k * NO + t];
        ev[t] = a;
    }
    __syncthreads();

    const float* Wp = Wp1 + (enc ? NO * PH : 0);
    a = 0.f;
    #pragma unroll 8
    for (int k = 0; k < NO; ++k) a += ev[k] * Wp[k * PH + t];
    (enc ? PB : PA)[row * PH + t] = a;
}

// ---------------- pair scores ----------------
__global__ __launch_bounds__(128) void k_pair(
    const float* __restrict__ PA, const float* __restrict__ PB,
    const float* __restrict__ bp1, const float* __restrict__ Wp2,
    const float* __restrict__ bp2, float* __restrict__ s_pair)
{
    const int i = blockIdx.x;
    const int j = threadIdx.x;
    __shared__ float pa[PH];
    __shared__ float b1s[PH];
    __shared__ float w2s[PH];
    pa[j]  = PA[i * PH + j];
    b1s[j] = bp1[j];
    w2s[j] = Wp2[j];
    __syncthreads();
    const float* pb = PB + j * PH;
    float acc = 0.f;
    #pragma unroll 8
    for (int c = 0; c < PH; ++c)
        acc += w2s[c] * fmaxf(pa[c] + pb[c] + b1s[c], 0.f);
    float z = acc + bp2[0];
    float sp = fmaxf(z, 0.f) + log1pf(__expf(-fabsf(z)));
    s_pair[i * 128 + j] = sp;
}

// ------- counting sort by length, DESCENDING, one block, LDS atomics -------
__global__ __launch_bounds__(1024) void k_sort(
    const int* __restrict__ lengths, int* __restrict__ perm)
{
    __shared__ int cnt[130];
    __shared__ int suf[130];
    const int t = threadIdx.x;
    if (t < 130) cnt[t] = 0;
    __syncthreads();
    for (int i = t; i < 16384; i += 1024) atomicAdd(&cnt[lengths[i]], 1);
    __syncthreads();
    if (t < 130) suf[t] = cnt[t];
    __syncthreads();
    for (int d = 1; d < 130; d <<= 1) {
        int v = 0;
        if (t < 130) { v = suf[t]; if (t + d < 130) v += suf[t + d]; }
        __syncthreads();
        if (t < 130) suf[t] = v;
        __syncthreads();
    }
    if (t < 129) cnt[t] = (t + 1 < 130) ? suf[t + 1] : 0;
    __syncthreads();
    for (int i = t; i < 16384; i += 1024) {
        int pos = atomicAdd(&cnt[lengths[i]], 1);
        perm[pos] = i;
    }
}

// ---- GRU, TRANSPOSED MFMA: D cols = pairs. 4 waves x 16 hidden cols ----
// grid 1024 x 256; wave w owns hidden cols [16w,16w+16); lane(q,n):
// pair = n, hidden cols = 16w + 4q + 0..3 (D rows). One ds_write_b64/lane/step.
__global__ __launch_bounds__(256, 4) void k_gru(
    const float* __restrict__ seqs, const int* __restrict__ lengths,
    const int* __restrict__ perm,
    const float* __restrict__ W_ih, const float* __restrict__ b_ih,
    const float* __restrict__ W_hh, const float* __restrict__ b_hh,
    const float* __restrict__ Ws, const float* __restrict__ bs,
    const float* __restrict__ s_pair, float* __restrict__ d_out)
{
    __shared__ __align__(16) f16 hbuf[2][16 * 72];   // [buf][pair][64 + 8 pad]
    __shared__ float red[64];
    const int tid = threadIdx.x;
    const int w  = tid >> 6;
    const int l  = tid & 63;
    const int q  = l >> 4;
    const int n  = l & 15;
    const int c  = w * 16 + n;          // W-frag column (m-row of A-tile)
    const int colbase = w * 16 + q * 4; // this lane's 4 hidden cols
    const int pb = blockIdx.x * 16;
    const float S_RZ = -1.4426950408889634f;   // -log2(e)
    const float S_N  =  2.8853900817779268f;   // 2*log2(e)

    // W fragments (identical gather to B-form; serve as A via m=lane&15):
    f16x8 wh[3][2], wi[3];
    #pragma unroll
    for (int g = 0; g < 3; ++g) {
        const int gb = g * 64;
        const float s = (g < 2) ? S_RZ : S_N;
        #pragma unroll
        for (int ks = 0; ks < 2; ++ks)
            #pragma unroll
            for (int j = 0; j < 8; ++j)
                wh[g][ks][j] = (f16)(W_hh[(ks * 32 + q * 8 + j) * 192 + gb + c] * s);
        #pragma unroll
        for (int j = 0; j < 8; ++j) {
            int k = q * 8 + j;
            wi[g][j] = (k < FE_N) ? (f16)(W_ih[k * 192 + gb + c] * s) : (f16)0.f;
        }
    }
    // per-reg bias C-vectors and Ws for this lane's 4 cols
    f32x4 c_r, c_z, c_hn, c_xn;
    float wsc[4];
    #pragma unroll
    for (int r = 0; r < 4; ++r) {
        int col = colbase + r;
        c_r[r]  = S_RZ * (b_ih[col] + b_hh[col]);
        c_z[r]  = S_RZ * (b_ih[64 + col] + b_hh[64 + col]);
        c_hn[r] = S_N * b_hh[128 + col];
        c_xn[r] = S_N * b_ih[128 + col];
        wsc[r]  = Ws[col];
    }
    const int myp   = perm[pb + n];      // this lane's pair
    const int mylen = lengths[myp];
    int ml = mylen;
    ml = max(ml, __shfl_xor(ml, 1));
    ml = max(ml, __shfl_xor(ml, 2));
    ml = max(ml, __shfl_xor(ml, 4));
    ml = max(ml, __shfl_xor(ml, 8));
    const int maxlen = __builtin_amdgcn_readfirstlane(ml);

    // zero h buffer 0 (2304 B = 144 x 16 B)
    {
        f16x8 z8 = {(f16)0, (f16)0, (f16)0, (f16)0, (f16)0, (f16)0, (f16)0, (f16)0};
        if (tid < 144) *(f16x8*)&hbuf[0][tid * 8] = z8;
    }

    // x: lanes q<2 stream pair n's feats [8q,8q+8) from global, 1-step prefetch
    const float4* xp = (const float4*)(seqs + (size_t)myp * (T_MAX * FE_N)) + q * 2;
    float4 xa = {0.f, 0.f, 0.f, 0.f}, xb = xa;
    if (q < 2) { xa = xp[0]; xb = xp[1]; }

    float hold[4] = {0.f, 0.f, 0.f, 0.f};
    const f16x8 zero8 = {(f16)0, (f16)0, (f16)0, (f16)0, (f16)0, (f16)0, (f16)0, (f16)0};
    __syncthreads();

    #pragma unroll 1
    for (int t = 0; t < maxlen; t += 2) {
        #pragma unroll
        for (int sub = 0; sub < 2; ++sub) {
            const int tt = t + sub;
            if (sub == 1 && tt >= maxlen) break;   // block-uniform
            const f16* hb  = hbuf[sub];
            f16*       hbw = hbuf[sub ^ 1];

            f16x8 ax = zero8;
            if (q < 2) {
                ax[0] = (f16)xa.x; ax[1] = (f16)xa.y; ax[2] = (f16)xa.z; ax[3] = (f16)xa.w;
                ax[4] = (f16)xb.x; ax[5] = (f16)xb.y; ax[6] = (f16)xb.z; ax[7] = (f16)xb.w;
                int tn = (tt + 1 < maxlen) ? (tt + 1) : tt;
                xa = xp[tn * 4];
                xb = xp[tn * 4 + 1];
            }
            f16x8 bh0 = *(const f16x8*)&hb[n * 72 + 8 * q];
            f16x8 bh1 = *(const f16x8*)&hb[n * 72 + 32 + 8 * q];

            f32x4 ar = __builtin_amdgcn_mfma_f32_16x16x32_f16(wh[0][0], bh0, c_r, 0, 0, 0);
            ar = __builtin_amdgcn_mfma_f32_16x16x32_f16(wh[0][1], bh1, ar, 0, 0, 0);
            ar = __builtin_amdgcn_mfma_f32_16x16x32_f16(wi[0],    ax,  ar, 0, 0, 0);
            f32x4 az = __builtin_amdgcn_mfma_f32_16x16x32_f16(wh[1][0], bh0, c_z, 0, 0, 0);
            az = __builtin_amdgcn_mfma_f32_16x16x32_f16(wh[1][1], bh1, az, 0, 0, 0);
            az = __builtin_amdgcn_mfma_f32_16x16x32_f16(wi[1],    ax,  az, 0, 0, 0);
            f32x4 hn = __builtin_amdgcn_mfma_f32_16x16x32_f16(wh[2][0], bh0, c_hn, 0, 0, 0);
            hn = __builtin_amdgcn_mfma_f32_16x16x32_f16(wh[2][1], bh1, hn, 0, 0, 0);
            f32x4 xn = __builtin_amdgcn_mfma_f32_16x16x32_f16(wi[2], ax, c_xn, 0, 0, 0);

            const bool live = (tt < mylen);
            #pragma unroll
            for (int r = 0; r < 4; ++r) {
                float rg    = __builtin_amdgcn_rcpf(1.f + __builtin_amdgcn_exp2f(ar[r]));
                float zg    = __builtin_amdgcn_rcpf(1.f + __builtin_amdgcn_exp2f(az[r]));
                float inner = fmaf(rg, hn[r], xn[r]);
                float nn    = fmaf(-2.f, __builtin_amdgcn_rcpf(1.f + __builtin_amdgcn_exp2f(inner)), 1.f);
                float hnew  = fmaf(zg, hold[r] - nn, nn);
                hold[r] = live ? hnew : hold[r];
            }
            f16x4 hv4;
            hv4[0] = (f16)hold[0];
            hv4[1] = (f16)hold[1];
            hv4[2] = (f16)hold[2];
            hv4[3] = (f16)hold[3];
            *(f16x4*)&hbw[n * 72 + colbase] = hv4;
            __syncthreads();
        }
    }

    // epilogue: p_seq = sigmoid(h @ Ws + bs); contrib = s_pair * p_seq
    float part = hold[0] * wsc[0] + hold[1] * wsc[1] +
                 hold[2] * wsc[2] + hold[3] * wsc[3];
    part += __shfl_xor(part, 16);
    part += __shfl_xor(part, 32);          // sum over q: wave-w partial for pair n
    if (l < 16) red[w * 16 + n] = part;
    __syncthreads();
    if (tid < 16) {
        float s = red[tid] + red[16 + tid] + red[32 + tid] + red[48 + tid];
        float pv = fast_sigmoid(s + bs[0]);
        float contrib = s_pair[perm[pb + tid]] * pv;
        #pragma unroll
        for (int off = 1; off < 16; off <<= 1)
            contrib += __shfl_xor(contrib, off);
        if (tid == 0) atomicAdd(d_out, contrib);
    }
}

extern "C" void kernel_launch(void* const* d_in, const int* in_sizes, int n_in,
                              void* d_out, int out_size, void* d_ws, size_t ws_size,
                              hipStream_t stream)
{
    const float* O_feats = (const float*)d_in[0];
    const float* D_feats = (const float*)d_in[1];
    const float* seqs    = (const float*)d_in[2];
    const int*   lengths = (const int*)d_in[3];
    const float* WO1 = (const float*)d_in[4];  const float* bO1 = (const float*)d_in[5];
    const float* WO2 = (const float*)d_in[6];  const float* bO2 = (const float*)d_in[7];
    const float* WO3 = (const float*)d_in[8];  const float* bO3 = (const float*)d_in[9];
    const float* WD1 = (const float*)d_in[10]; const float* bD1 = (const float*)d_in[11];
    const float* WD2 = (const float*)d_in[12]; const float* bD2 = (const float*)d_in[13];
    const float* WD3 = (const float*)d_in[14]; const float* bD3 = (const float*)d_in[15];
    const float* Wp1 = (const float*)d_in[16]; const float* bp1 = (const float*)d_in[17];
    const float* Wp2 = (const float*)d_in[18]; const float* bp2 = (const float*)d_in[19];
    const float* W_ih = (const float*)d_in[20]; const float* b_ih = (const float*)d_in[21];
    const float* W_hh = (const float*)d_in[22]; const float* b_hh = (const float*)d_in[23];
    const float* Ws   = (const float*)d_in[24]; const float* bs   = (const float*)d_in[25];

    float* out    = (float*)d_out;
    float* PA     = (float*)d_ws;              // 16384 f
    float* PB     = PA + 128 * 128;            // 16384 f
    float* s_pair = PB + 128 * 128;            // 16384 f
    int*   perm   = (int*)(s_pair + 16384);    // 16384 i

    k_enc<<<256, 128, 0, stream>>>(O_feats, D_feats,
                                   WO1, bO1, WO2, bO2, WO3, bO3,
                                   WD1, bD1, WD2, bD2, WD3, bD3,
                                   Wp1, PA, PB, out);
    k_pair<<<128, 128, 0, stream>>>(PA, PB, bp1, Wp2, bp2, s_pair);
    k_sort<<<1, 1024, 0, stream>>>(lengths, perm);
    k_gru<<<1024, 256, 0, stream>>>(seqs, lengths, perm, W_ih, b_ih, W_hh, b_hh,
                                    Ws, bs, s_pair, out);
}